// Round 6
// baseline (372.101 us; speedup 1.0000x reference)
//
#include <hip/hip_runtime.h>
#include <cstdint>
#include <cstddef>

#define NSEG 32769      // N_NODES + 1 (row 0 is the zero row)
#define NNODES 32768
#define NE 262144

using f4 = float4;

// ---------------- static device scratch ----------------
// tfh layout: ((row*64 + lane)*4 + slot), bf16. slots {0,1,2} = out cols c*64+lane,
// slot 3 = h_orig (written once by k_emb, never overwritten).
__device__ ushort g_tfh[(size_t)NSEG * 64 * 4];
__device__ ushort g_msg0h[(size_t)NE * 64];       // bf16 row-major
__device__ float  g_msum[(size_t)NSEG * 192];
__device__ float  g_qe[NE];
__device__ float  g_q[NSEG];
__device__ float  g_p0[3][NSEG];
__device__ float  g_p1[3][NSEG];
__device__ float  g_w2[3][256];                   // w2 = W @ a2 in [0,d); c = a2.b at [255]
__device__ float  g_wq10[10];                     // W_dist @ w2_0
__device__ float  g_cq;                           // b_dist.w2_0 + c0
__device__ int    g_counts[NSEG];
__device__ int    g_excl[NSEG];
__device__ int    g_bsum[1024];
__device__ int    g_rowptr[NSEG + 1];
__device__ int    g_cur[NSEG];
__device__ int    g_csr[NE];

#define WREDUCE(x) { x += __shfl_xor(x, 32); x += __shfl_xor(x, 16); \
                     x += __shfl_xor(x, 8);  x += __shfl_xor(x, 4);  \
                     x += __shfl_xor(x, 2);  x += __shfl_xor(x, 1); }
#define WREDMAX(x) { x = fmaxf(x, __shfl_xor(x, 32)); x = fmaxf(x, __shfl_xor(x, 16)); \
                     x = fmaxf(x, __shfl_xor(x, 8));  x = fmaxf(x, __shfl_xor(x, 4));  \
                     x = fmaxf(x, __shfl_xor(x, 2));  x = fmaxf(x, __shfl_xor(x, 1)); }

__device__ __forceinline__ ushort f2bf(float x) {
    uint u = __float_as_uint(x);
    u += 0x7FFF + ((u >> 16) & 1);
    return (ushort)(u >> 16);
}
__device__ __forceinline__ float bflo(uint u) { return __uint_as_float(u << 16); }
__device__ __forceinline__ float bfhi(uint u) { return __uint_as_float(u & 0xFFFF0000u); }

// ---------------- init: zero counts/cur ----------------
__global__ void k_init() {
    int i = blockIdx.x * 256 + threadIdx.x;
    if (i < NSEG) { g_counts[i] = 0; g_cur[i] = 0; }
}

// -------- h_orig (bf16, slot 3 of tfh) = node_feats @ W_emb + b_emb ; fused p0/p1 --------
__global__ void k_emb(const float* __restrict__ node_feats,
                      const float* __restrict__ W, const float* __restrict__ b,
                      const float* __restrict__ a0, const float* __restrict__ a1,
                      const float* __restrict__ a2) {
    __shared__ float Ws[9 * 64];
    __shared__ float fs[4][9];
    int tid = threadIdx.x;
    for (int i = tid; i < 576; i += 256) Ws[i] = W[i];
    int r0 = blockIdx.x * 4;
    if (tid < 36) {
        int r = r0 + tid / 9, k = tid % 9;
        float v = 0.f;
        if (r >= 1 && r <= NNODES) v = node_feats[(size_t)(r - 1) * 9 + k];
        fs[tid / 9][k] = v;
    }
    __syncthreads();
    int r = tid >> 6, j = tid & 63;
    int row = r0 + r;
    if (row >= NSEG) return;
    float acc = b[j];
#pragma unroll
    for (int k = 0; k < 9; k++) acc += fs[r][k] * Ws[k * 64 + j];
    float v = (row == 0) ? 0.f : acc;
    g_tfh[((size_t)row * 64 + j) * 4 + 3] = f2bf(v);
    const float* A[3] = {a0, a1, a2};
#pragma unroll
    for (int i = 0; i < 3; i++) {
        float d0 = v * A[i][j];
        WREDUCE(d0);
        if (j == 0) g_p0[i][row] = d0;
        float d1 = v * A[i][64 + j];
        WREDUCE(d1);
        if (j == 0) g_p1[i][row] = d1;
    }
}

// ---------------- per-iter prep: w2 = W @ a2 ; c = a2.b (one block per iter) ----------------
__global__ void k_prep_all(const float* __restrict__ W0, const float* __restrict__ W1,
                           const float* __restrict__ W2, const float* __restrict__ a0,
                           const float* __restrict__ a1, const float* __restrict__ a2,
                           const float* __restrict__ b0, const float* __restrict__ b1,
                           const float* __restrict__ b2) {
    int it = blockIdx.x;
    const float* W = it == 0 ? W0 : (it == 1 ? W1 : W2);
    const float* a = it == 0 ? a0 : (it == 1 ? a1 : a2);
    const float* bias = it == 0 ? b0 : (it == 1 ? b1 : b2);
    int d = 64 * (it + 1);
    int k = threadIdx.x;
    if (k < d) {
        float s = 0.f;
        for (int j = 0; j < d; j++) s += W[(size_t)k * d + j] * a[128 + j];
        g_w2[it][k] = s;
    } else if (k == 255) {
        float c = 0.f;
        for (int j = 0; j < d; j++) c += a[128 + j] * bias[j];
        g_w2[it][255] = c;
    }
}

// ---------------- prep2: wq10 = W_dist @ w2_0 ; cq = b_dist.w2_0 + c0 ----------------
__global__ void k_prep2(const float* __restrict__ Wd, const float* __restrict__ bd) {
    int k = threadIdx.x;
    if (k < 10) {
        float s = 0.f;
        for (int j = 0; j < 64; j++) s += Wd[(size_t)k * 64 + j] * g_w2[0][j];
        g_wq10[k] = s;
    } else if (k == 63) {
        float s = 0.f;
        for (int j = 0; j < 64; j++) s += bd[j] * g_w2[0][j];
        g_cq = s + g_w2[0][255];
    }
}

// -------- msg0 (bf16) = [fdg | rij] @ W_dist + b_dist ; qe = x.wq10 + cq --------
__global__ __launch_bounds__(256) void k_msg0(const float* __restrict__ fdg,
                                              const float* __restrict__ rij,
                                              const float* __restrict__ W,
                                              const float* __restrict__ b) {
    __shared__ float Ws[10 * 64];
    __shared__ float bs[64];
    __shared__ float fs[64][10];
    int tid = threadIdx.x;
    for (int i = tid; i < 640; i += 256) Ws[i] = W[i];
    if (tid < 64) bs[tid] = b[tid];
    int e0 = blockIdx.x * 64;
    for (int i = tid; i < 576; i += 256) fs[i / 9][i % 9] = fdg[(size_t)e0 * 9 + i];
    if (tid < 64) fs[tid][9] = rij[e0 + tid];
    __syncthreads();
    int j = tid & 63;
#pragma unroll 4
    for (int p = 0; p < 16; p++) {
        int r = p * 4 + (tid >> 6);
        int e = e0 + r;
        float acc = bs[j];
#pragma unroll
        for (int k = 0; k < 10; k++) acc += fs[r][k] * Ws[k * 64 + j];
        g_msg0h[(size_t)e * 64 + j] = f2bf(acc);
        if (j == 0) {
            float q = g_cq;
#pragma unroll
            for (int k = 0; k < 10; k++) q += fs[r][k] * g_wq10[k];
            g_qe[e] = q;
        }
    }
}

// ---------------- CSR build over b_scope ----------------
__global__ void k_hist(const int* __restrict__ bs) {
    int e = blockIdx.x * 256 + threadIdx.x;
    if (e < NE) atomicAdd(&g_counts[bs[e]], 1);
}

__global__ void k_scan1() {
    __shared__ int s[256];
    int t = threadIdx.x, i = blockIdx.x * 256 + t;
    int v = (i < NSEG) ? g_counts[i] : 0;
    s[t] = v; __syncthreads();
    for (int off = 1; off < 256; off <<= 1) {
        int tmp = (t >= off) ? s[t - off] : 0;
        __syncthreads();
        s[t] += tmp;
        __syncthreads();
    }
    if (i < NSEG) g_excl[i] = s[t] - v;
    if (t == 255) g_bsum[blockIdx.x] = s[255];
}

__global__ void k_scan2(int nb) {
    __shared__ int s[256];
    int t = threadIdx.x;
    int v = (t < nb) ? g_bsum[t] : 0;
    s[t] = v; __syncthreads();
    for (int off = 1; off < 256; off <<= 1) {
        int tmp = (t >= off) ? s[t - off] : 0;
        __syncthreads();
        s[t] += tmp;
        __syncthreads();
    }
    if (t < nb) g_bsum[t] = s[t] - v;   // exclusive
}

__global__ void k_scan3() {
    int i = blockIdx.x * 256 + threadIdx.x;
    if (i < NSEG) g_rowptr[i] = g_excl[i] + g_bsum[i >> 8];
    if (i == NSEG) g_rowptr[NSEG] = NE;
}

__global__ void k_scatter(const int* __restrict__ bs) {
    int e = blockIdx.x * 256 + threadIdx.x;
    if (e < NE) {
        int seg = bs[e];
        int pos = g_rowptr[seg] + atomicAdd(&g_cur[seg], 1);
        g_csr[pos] = e;
    }
}

// ---------------- per-node q = tf . w2 + c  (after iter 1 and 2 GEMMs) ----------------
__global__ void k_nodedot(int it) {
    int tid = threadIdx.x;
    int n = blockIdx.x * 4 + (tid >> 6), lane = tid & 63;
    if (n >= NSEG) return;
    uint2 u = *(const uint2*)&g_tfh[((size_t)n * 64 + lane) * 4];
    float s;
    if (it == 1)
        s = bflo(u.x) * g_w2[1][lane] + bfhi(u.y) * g_w2[1][64 + lane];
    else
        s = bflo(u.x) * g_w2[2][lane] + bfhi(u.x) * g_w2[2][64 + lane] +
            bfhi(u.y) * g_w2[2][128 + lane];
    WREDUCE(s);
    if (lane == 0) g_q[n] = s + g_w2[it][255];
}

// -------- segment softmax (logits fused) + alpha-weighted message sum --------
// component c of the gathered message maps to tfh slot (c == NCM-1 ? 3 : c)
template <int NCM, bool GATHER>
__global__ __launch_bounds__(256) void k_attend2(const int* __restrict__ g1,
                                                 const int* __restrict__ g2,
                                                 const int* __restrict__ see, int it) {
    int lane = threadIdx.x & 63;
    int seg = blockIdx.x * 4 + (threadIdx.x >> 6);
    if (seg >= NSEG) return;
    int beg = g_rowptr[seg], end = g_rowptr[seg + 1];
    int cnt = end - beg;
    float acc[NCM];
#pragma unroll
    for (int c = 0; c < NCM; c++) acc[c] = 0.f;

    if (cnt > 0 && cnt <= 64) {
        float l = -1e30f;
        int i1 = 0, i2 = 0;
        if (lane < cnt) {
            int e = g_csr[beg + lane];
            float qv;
            if (GATHER) {
                i1 = g1[e]; i2 = g2[e];
                qv = 0.5f * (g_q[i1] + g_q[i2]);
            } else {
                i1 = e;
                qv = g_qe[e];
            }
            l = qv + g_p0[it][see[2 * (size_t)e]] + g_p1[it][see[2 * (size_t)e + 1]];
            l = l > 0.f ? l : 0.2f * l;
        }
        float m = l;
        WREDMAX(m);
        float ex = (lane < cnt) ? __expf(l - m) : 0.f;
        float den = ex;
        WREDUCE(den);
        float w = ex / den;
        for (int t = 0; t < cnt; t++) {
            float wt = __shfl(w, t);
            if (GATHER) {
                int a1 = __shfl(i1, t), a2 = __shfl(i2, t);
                float wh = 0.5f * wt;
                uint2 ua = *(const uint2*)&g_tfh[((size_t)a1 * 64 + lane) * 4];
                uint2 ub = *(const uint2*)&g_tfh[((size_t)a2 * 64 + lane) * 4];
                if (NCM == 3) {
                    acc[0] += wh * (bflo(ua.x) + bflo(ub.x));
                    acc[1] += wh * (bfhi(ua.x) + bfhi(ub.x));
                    acc[2] += wh * (bfhi(ua.y) + bfhi(ub.y));
                } else {
                    acc[0] += wh * (bflo(ua.x) + bflo(ub.x));
                    acc[1] += wh * (bfhi(ua.y) + bfhi(ub.y));
                }
            } else {
                int ae = __shfl(i1, t);
                acc[0] += wt * bflo((uint)g_msg0h[(size_t)ae * 64 + lane]);
            }
        }
    } else if (cnt > 64) {
        // rare fallback: two-pass serial
        float m = -1e30f;
        for (int t = beg + lane; t < end; t += 64) {
            int e = g_csr[t];
            float qv = GATHER ? 0.5f * (g_q[g1[e]] + g_q[g2[e]]) : g_qe[e];
            float l = qv + g_p0[it][see[2 * (size_t)e]] + g_p1[it][see[2 * (size_t)e + 1]];
            l = l > 0.f ? l : 0.2f * l;
            m = fmaxf(m, l);
        }
        WREDMAX(m);
        float den = 0.f;
        for (int t = beg + lane; t < end; t += 64) {
            int e = g_csr[t];
            float qv = GATHER ? 0.5f * (g_q[g1[e]] + g_q[g2[e]]) : g_qe[e];
            float l = qv + g_p0[it][see[2 * (size_t)e]] + g_p1[it][see[2 * (size_t)e + 1]];
            l = l > 0.f ? l : 0.2f * l;
            den += __expf(l - m);
        }
        WREDUCE(den);
        float rden = 1.f / den;
        for (int t = beg; t < end; t++) {
            int e = g_csr[t];
            float qv = GATHER ? 0.5f * (g_q[g1[e]] + g_q[g2[e]]) : g_qe[e];
            float l = qv + g_p0[it][see[2 * (size_t)e]] + g_p1[it][see[2 * (size_t)e + 1]];
            l = l > 0.f ? l : 0.2f * l;
            float w = __expf(l - m) * rden;
            if (GATHER) {
                float wh = 0.5f * w;
                uint2 ua = *(const uint2*)&g_tfh[((size_t)g1[e] * 64 + lane) * 4];
                uint2 ub = *(const uint2*)&g_tfh[((size_t)g2[e] * 64 + lane) * 4];
                if (NCM == 3) {
                    acc[0] += wh * (bflo(ua.x) + bflo(ub.x));
                    acc[1] += wh * (bfhi(ua.x) + bfhi(ub.x));
                    acc[2] += wh * (bfhi(ua.y) + bfhi(ub.y));
                } else {
                    acc[0] += wh * (bflo(ua.x) + bflo(ub.x));
                    acc[1] += wh * (bfhi(ua.y) + bfhi(ub.y));
                }
            } else {
                acc[0] += w * bflo((uint)g_msg0h[(size_t)e * 64 + lane]);
            }
        }
    }
#pragma unroll
    for (int c = 0; c < NCM; c++)
        g_msum[(size_t)seg * 192 + lane + 64 * c] = acc[c];
}

// ----- segment GEMM (32-row x 64-col tiles): tfh slot by = mask*elu(msum @ W + b) -----
template <int NC>
__global__ __launch_bounds__(256) void k_gemm2(const float* __restrict__ W,
                                               const float* __restrict__ bias) {
    constexpr int D = 64 * NC;
    __shared__ float As[32][17];
    __shared__ float Bs[16][64];
    int tid = threadIdx.x;
    int rb0 = blockIdx.x * 32;
    int cslot = blockIdx.y;          // column block = tfh slot
    int cb0 = cslot * 64;
    int ty = tid >> 4, tx = tid & 15;
    float acc[2][4] = {{0.f, 0.f, 0.f, 0.f}, {0.f, 0.f, 0.f, 0.f}};
    int arow = tid >> 3, ak = (tid & 7) * 2;
    for (int kk = 0; kk < D; kk += 16) {
        float2 av = make_float2(0.f, 0.f);
        if (rb0 + arow < NSEG)
            av = *(const float2*)&g_msum[(size_t)(rb0 + arow) * 192 + kk + ak];
        As[arow][ak] = av.x; As[arow][ak + 1] = av.y;
        f4 bv = *(const f4*)&W[(size_t)(kk + ty) * D + cb0 + tx * 4];
        Bs[ty][tx * 4 + 0] = bv.x; Bs[ty][tx * 4 + 1] = bv.y;
        Bs[ty][tx * 4 + 2] = bv.z; Bs[ty][tx * 4 + 3] = bv.w;
        __syncthreads();
#pragma unroll
        for (int k = 0; k < 16; k++) {
            float a0 = As[ty * 2][k], a1 = As[ty * 2 + 1][k];
            f4 b = *(const f4*)&Bs[k][tx * 4];
            acc[0][0] += a0 * b.x; acc[0][1] += a0 * b.y;
            acc[0][2] += a0 * b.z; acc[0][3] += a0 * b.w;
            acc[1][0] += a1 * b.x; acc[1][1] += a1 * b.y;
            acc[1][2] += a1 * b.z; acc[1][3] += a1 * b.w;
        }
        __syncthreads();
    }
#pragma unroll
    for (int r = 0; r < 2; r++) {
        int row = rb0 + ty * 2 + r;
        if (row >= NSEG) continue;
        bool nonempty = g_rowptr[row + 1] > g_rowptr[row];
#pragma unroll
        for (int j = 0; j < 4; j++) {
            float v = acc[r][j] + bias[cb0 + tx * 4 + j];
            if (!nonempty) v = 0.f;
            v = v > 0.f ? v : (__expf(v) - 1.f);
            g_tfh[((size_t)row * 64 + tx * 4 + j) * 4 + cslot] = f2bf(v);
        }
    }
}

// ---------------- final: per-molecule gather-sum (bf16 in, f32 out) ----------------
__global__ void k_final(const int* __restrict__ lscope, float* __restrict__ out) {
    __shared__ int idx[32];
    __shared__ float sm[4][256];
    int m = blockIdx.x, tid = threadIdx.x, w = tid >> 6, lane = tid & 63;
    if (tid < 32) idx[tid] = lscope[m * 32 + tid];
    __syncthreads();
    float a0 = 0.f, a1 = 0.f, a2 = 0.f, a3 = 0.f;
#pragma unroll
    for (int j = w * 8; j < w * 8 + 8; j++) {
        uint2 u = *(const uint2*)&g_tfh[((size_t)idx[j] * 64 + lane) * 4];
        a0 += bflo(u.x); a1 += bfhi(u.x); a2 += bflo(u.y); a3 += bfhi(u.y);
    }
    sm[w][lane] = a0; sm[w][64 + lane] = a1; sm[w][128 + lane] = a2; sm[w][192 + lane] = a3;
    __syncthreads();
    out[(size_t)m * 256 + tid] = sm[0][tid] + sm[1][tid] + sm[2][tid] + sm[3][tid];
}

extern "C" void kernel_launch(void* const* d_in, const int* in_sizes, int n_in,
                              void* d_out, int out_size, void* d_ws, size_t ws_size,
                              hipStream_t stream) {
    const float* node_feats = (const float*)d_in[0];
    const float* fdg        = (const float*)d_in[1];
    const float* rij        = (const float*)d_in[2];
    const int*   see        = (const int*)d_in[3];
    const int*   b_scope    = (const int*)d_in[4];
    const int*   scope_up   = (const int*)d_in[5];
    const int*   scope_lig  = (const int*)d_in[6];
    const int*   l_scope    = (const int*)d_in[7];
    const float* W_emb      = (const float*)d_in[8];
    const float* b_emb      = (const float*)d_in[9];
    const float* W_dist     = (const float*)d_in[10];
    const float* b_dist     = (const float*)d_in[11];
    const float* fc_W[3]   = {(const float*)d_in[12], (const float*)d_in[15], (const float*)d_in[18]};
    const float* fc_b[3]   = {(const float*)d_in[13], (const float*)d_in[16], (const float*)d_in[19]};
    const float* attn_a[3] = {(const float*)d_in[14], (const float*)d_in[17], (const float*)d_in[20]};

    k_init<<<129, 256, 0, stream>>>();
    k_emb<<<8193, 256, 0, stream>>>(node_feats, W_emb, b_emb,
                                    attn_a[0], attn_a[1], attn_a[2]);
    k_prep_all<<<3, 256, 0, stream>>>(fc_W[0], fc_W[1], fc_W[2],
                                      attn_a[0], attn_a[1], attn_a[2],
                                      fc_b[0], fc_b[1], fc_b[2]);
    k_prep2<<<1, 64, 0, stream>>>(W_dist, b_dist);
    k_msg0<<<NE / 64, 256, 0, stream>>>(fdg, rij, W_dist, b_dist);
    k_hist<<<NE / 256, 256, 0, stream>>>(b_scope);
    k_scan1<<<129, 256, 0, stream>>>();
    k_scan2<<<1, 256, 0, stream>>>(129);
    k_scan3<<<129, 256, 0, stream>>>();
    k_scatter<<<NE / 256, 256, 0, stream>>>(b_scope);

    // iter 0 (message width 64)
    k_attend2<1, false><<<8193, 256, 0, stream>>>(nullptr, nullptr, see, 0);
    k_gemm2<1><<<dim3(1025, 1), 256, 0, stream>>>(fc_W[0], fc_b[0]);
    k_nodedot<<<8193, 256, 0, stream>>>(1);
    // iter 1 (message width 128)
    k_attend2<2, true><<<8193, 256, 0, stream>>>(scope_lig, scope_up, see, 1);
    k_gemm2<2><<<dim3(1025, 2), 256, 0, stream>>>(fc_W[1], fc_b[1]);
    k_nodedot<<<8193, 256, 0, stream>>>(2);
    // iter 2 (message width 192)
    k_attend2<3, true><<<8193, 256, 0, stream>>>(scope_lig, scope_up, see, 2);
    k_gemm2<3><<<dim3(1025, 3), 256, 0, stream>>>(fc_W[2], fc_b[2]);

    k_final<<<2048, 256, 0, stream>>>(l_scope, (float*)d_out);
}

// Round 7
// 339.994 us; speedup vs baseline: 1.0944x; 1.0944x over previous
//
#include <hip/hip_runtime.h>
#include <cstdint>
#include <cstddef>

#define NSEG 32769      // N_NODES + 1 (row 0 is the zero row)
#define NNODES 32768
#define NE 262144
#define PSZ ((size_t)NSEG * 64)   // one tf plane

using f4 = float4;

// ---------------- static device scratch ----------------
// tf planes: g_tfp[plane*PSZ + row*64 + lane], bf16.
// planes 0..2 = GEMM output cols (c*64+lane); plane 3 = h_orig (written once).
__device__ ushort g_tfp[4 * PSZ];
__device__ ushort g_msg0h[(size_t)NE * 64];       // bf16 row-major
__device__ ushort g_msumh[(size_t)NSEG * 192];    // bf16 row-major (K width 192)
__device__ float  g_qe[NE];
__device__ float  g_q[NSEG];
__device__ float  g_p0[3][NSEG];
__device__ float  g_p1[3][NSEG];
__device__ float  g_w2[3][256];                   // w2 = W @ a2 in [0,d); c = a2.b at [255]
__device__ float  g_wq10[10];                     // W_dist @ w2_0
__device__ float  g_cq;                           // b_dist.w2_0 + c0
__device__ int    g_counts[NSEG];
__device__ int    g_excl[NSEG];
__device__ int    g_bsum[1024];
__device__ int    g_rowptr[NSEG + 1];
__device__ int    g_cur[NSEG];
__device__ int    g_csr[NE];

#define WREDUCE(x) { x += __shfl_xor(x, 32); x += __shfl_xor(x, 16); \
                     x += __shfl_xor(x, 8);  x += __shfl_xor(x, 4);  \
                     x += __shfl_xor(x, 2);  x += __shfl_xor(x, 1); }
#define WREDMAX(x) { x = fmaxf(x, __shfl_xor(x, 32)); x = fmaxf(x, __shfl_xor(x, 16)); \
                     x = fmaxf(x, __shfl_xor(x, 8));  x = fmaxf(x, __shfl_xor(x, 4));  \
                     x = fmaxf(x, __shfl_xor(x, 2));  x = fmaxf(x, __shfl_xor(x, 1)); }

__device__ __forceinline__ ushort f2bf(float x) {
    uint u = __float_as_uint(x);
    u += 0x7FFF + ((u >> 16) & 1);
    return (ushort)(u >> 16);
}
__device__ __forceinline__ float bfs(ushort u) { return __uint_as_float(((uint)u) << 16); }

// ---------------- init: zero counts/cur ----------------
__global__ void k_init() {
    int i = blockIdx.x * 256 + threadIdx.x;
    if (i < NSEG) { g_counts[i] = 0; g_cur[i] = 0; }
}

// -------- h_orig (bf16, plane 3) = node_feats @ W_emb + b_emb ; fused p0/p1 --------
__global__ void k_emb(const float* __restrict__ node_feats,
                      const float* __restrict__ W, const float* __restrict__ b,
                      const float* __restrict__ a0, const float* __restrict__ a1,
                      const float* __restrict__ a2) {
    __shared__ float Ws[9 * 64];
    __shared__ float fs[4][9];
    int tid = threadIdx.x;
    for (int i = tid; i < 576; i += 256) Ws[i] = W[i];
    int r0 = blockIdx.x * 4;
    if (tid < 36) {
        int r = r0 + tid / 9, k = tid % 9;
        float v = 0.f;
        if (r >= 1 && r <= NNODES) v = node_feats[(size_t)(r - 1) * 9 + k];
        fs[tid / 9][k] = v;
    }
    __syncthreads();
    int r = tid >> 6, j = tid & 63;
    int row = r0 + r;
    if (row >= NSEG) return;
    float acc = b[j];
#pragma unroll
    for (int k = 0; k < 9; k++) acc += fs[r][k] * Ws[k * 64 + j];
    float v = (row == 0) ? 0.f : acc;
    g_tfp[3 * PSZ + (size_t)row * 64 + j] = f2bf(v);
    const float* A[3] = {a0, a1, a2};
#pragma unroll
    for (int i = 0; i < 3; i++) {
        float d0 = v * A[i][j];
        WREDUCE(d0);
        if (j == 0) g_p0[i][row] = d0;
        float d1 = v * A[i][64 + j];
        WREDUCE(d1);
        if (j == 0) g_p1[i][row] = d1;
    }
}

// ---------------- per-iter prep: w2 = W @ a2 ; c = a2.b (one block per iter) ----------------
__global__ void k_prep_all(const float* __restrict__ W0, const float* __restrict__ W1,
                           const float* __restrict__ W2, const float* __restrict__ a0,
                           const float* __restrict__ a1, const float* __restrict__ a2,
                           const float* __restrict__ b0, const float* __restrict__ b1,
                           const float* __restrict__ b2) {
    int it = blockIdx.x;
    const float* W = it == 0 ? W0 : (it == 1 ? W1 : W2);
    const float* a = it == 0 ? a0 : (it == 1 ? a1 : a2);
    const float* bias = it == 0 ? b0 : (it == 1 ? b1 : b2);
    int d = 64 * (it + 1);
    int k = threadIdx.x;
    if (k < d) {
        float s = 0.f;
        for (int j = 0; j < d; j++) s += W[(size_t)k * d + j] * a[128 + j];
        g_w2[it][k] = s;
    } else if (k == 255) {
        float c = 0.f;
        for (int j = 0; j < d; j++) c += a[128 + j] * bias[j];
        g_w2[it][255] = c;
    }
}

// ---------------- prep2: wq10 = W_dist @ w2_0 ; cq = b_dist.w2_0 + c0 ----------------
__global__ void k_prep2(const float* __restrict__ Wd, const float* __restrict__ bd) {
    int k = threadIdx.x;
    if (k < 10) {
        float s = 0.f;
        for (int j = 0; j < 64; j++) s += Wd[(size_t)k * 64 + j] * g_w2[0][j];
        g_wq10[k] = s;
    } else if (k == 63) {
        float s = 0.f;
        for (int j = 0; j < 64; j++) s += bd[j] * g_w2[0][j];
        g_cq = s + g_w2[0][255];
    }
}

// -------- msg0 (bf16) = [fdg | rij] @ W_dist + b_dist ; qe = x.wq10 + cq --------
__global__ __launch_bounds__(256) void k_msg0(const float* __restrict__ fdg,
                                              const float* __restrict__ rij,
                                              const float* __restrict__ W,
                                              const float* __restrict__ b) {
    __shared__ float Ws[10 * 64];
    __shared__ float bs[64];
    __shared__ float fs[64][10];
    int tid = threadIdx.x;
    for (int i = tid; i < 640; i += 256) Ws[i] = W[i];
    if (tid < 64) bs[tid] = b[tid];
    int e0 = blockIdx.x * 64;
    for (int i = tid; i < 576; i += 256) fs[i / 9][i % 9] = fdg[(size_t)e0 * 9 + i];
    if (tid < 64) fs[tid][9] = rij[e0 + tid];
    __syncthreads();
    int j = tid & 63;
#pragma unroll 4
    for (int p = 0; p < 16; p++) {
        int r = p * 4 + (tid >> 6);
        int e = e0 + r;
        float acc = bs[j];
#pragma unroll
        for (int k = 0; k < 10; k++) acc += fs[r][k] * Ws[k * 64 + j];
        g_msg0h[(size_t)e * 64 + j] = f2bf(acc);
        if (j == 0) {
            float q = g_cq;
#pragma unroll
            for (int k = 0; k < 10; k++) q += fs[r][k] * g_wq10[k];
            g_qe[e] = q;
        }
    }
}

// ---------------- CSR build over b_scope ----------------
__global__ void k_hist(const int* __restrict__ bs) {
    int e = blockIdx.x * 256 + threadIdx.x;
    if (e < NE) atomicAdd(&g_counts[bs[e]], 1);
}

__global__ void k_scan1() {
    __shared__ int s[256];
    int t = threadIdx.x, i = blockIdx.x * 256 + t;
    int v = (i < NSEG) ? g_counts[i] : 0;
    s[t] = v; __syncthreads();
    for (int off = 1; off < 256; off <<= 1) {
        int tmp = (t >= off) ? s[t - off] : 0;
        __syncthreads();
        s[t] += tmp;
        __syncthreads();
    }
    if (i < NSEG) g_excl[i] = s[t] - v;
    if (t == 255) g_bsum[blockIdx.x] = s[255];
}

__global__ void k_scan2(int nb) {
    __shared__ int s[256];
    int t = threadIdx.x;
    int v = (t < nb) ? g_bsum[t] : 0;
    s[t] = v; __syncthreads();
    for (int off = 1; off < 256; off <<= 1) {
        int tmp = (t >= off) ? s[t - off] : 0;
        __syncthreads();
        s[t] += tmp;
        __syncthreads();
    }
    if (t < nb) g_bsum[t] = s[t] - v;   // exclusive
}

__global__ void k_scan3() {
    int i = blockIdx.x * 256 + threadIdx.x;
    if (i < NSEG) g_rowptr[i] = g_excl[i] + g_bsum[i >> 8];
    if (i == NSEG) g_rowptr[NSEG] = NE;
}

__global__ void k_scatter(const int* __restrict__ bs) {
    int e = blockIdx.x * 256 + threadIdx.x;
    if (e < NE) {
        int seg = bs[e];
        int pos = g_rowptr[seg] + atomicAdd(&g_cur[seg], 1);
        g_csr[pos] = e;
    }
}

// ---------------- per-node q = tf . w2 + c  (after iter 1 and 2 GEMMs) ----------------
__global__ void k_nodedot(int it) {
    int tid = threadIdx.x;
    int n = blockIdx.x * 4 + (tid >> 6), lane = tid & 63;
    if (n >= NSEG) return;
    size_t base = (size_t)n * 64 + lane;
    float s;
    if (it == 1)
        s = bfs(g_tfp[base]) * g_w2[1][lane] +
            bfs(g_tfp[3 * PSZ + base]) * g_w2[1][64 + lane];
    else
        s = bfs(g_tfp[base]) * g_w2[2][lane] +
            bfs(g_tfp[PSZ + base]) * g_w2[2][64 + lane] +
            bfs(g_tfp[3 * PSZ + base]) * g_w2[2][128 + lane];
    WREDUCE(s);
    if (lane == 0) g_q[n] = s + g_w2[it][255];
}

// -------- segment softmax (logits fused) + alpha-weighted message sum --------
// message component c -> tf plane (c == NCM-1 ? 3 : c)
template <int NCM, bool GATHER>
__global__ __launch_bounds__(256) void k_attend2(const int* __restrict__ g1,
                                                 const int* __restrict__ g2,
                                                 const int* __restrict__ see, int it) {
    int lane = threadIdx.x & 63;
    int seg = blockIdx.x * 4 + (threadIdx.x >> 6);
    if (seg >= NSEG) return;
    int beg = g_rowptr[seg], end = g_rowptr[seg + 1];
    int cnt = end - beg;
    float acc[NCM];
#pragma unroll
    for (int c = 0; c < NCM; c++) acc[c] = 0.f;

    if (cnt > 0 && cnt <= 64) {
        float l = -1e30f;
        int i1 = 0, i2 = 0;
        if (lane < cnt) {
            int e = g_csr[beg + lane];
            float qv;
            if (GATHER) {
                i1 = g1[e]; i2 = g2[e];
                qv = 0.5f * (g_q[i1] + g_q[i2]);
            } else {
                i1 = e;
                qv = g_qe[e];
            }
            l = qv + g_p0[it][see[2 * (size_t)e]] + g_p1[it][see[2 * (size_t)e + 1]];
            l = l > 0.f ? l : 0.2f * l;
        }
        float m = l;
        WREDMAX(m);
        float ex = (lane < cnt) ? __expf(l - m) : 0.f;
        float den = ex;
        WREDUCE(den);
        float w = ex / den;
        for (int t = 0; t < cnt; t++) {
            float wt = __shfl(w, t);
            if (GATHER) {
                int a1 = __shfl(i1, t), a2 = __shfl(i2, t);
                float wh = 0.5f * wt;
                size_t b1 = (size_t)a1 * 64 + lane, b2 = (size_t)a2 * 64 + lane;
                if (NCM == 3) {
                    acc[0] += wh * (bfs(g_tfp[b1]) + bfs(g_tfp[b2]));
                    acc[1] += wh * (bfs(g_tfp[PSZ + b1]) + bfs(g_tfp[PSZ + b2]));
                    acc[2] += wh * (bfs(g_tfp[3 * PSZ + b1]) + bfs(g_tfp[3 * PSZ + b2]));
                } else {
                    acc[0] += wh * (bfs(g_tfp[b1]) + bfs(g_tfp[b2]));
                    acc[1] += wh * (bfs(g_tfp[3 * PSZ + b1]) + bfs(g_tfp[3 * PSZ + b2]));
                }
            } else {
                int ae = __shfl(i1, t);
                acc[0] += wt * bfs(g_msg0h[(size_t)ae * 64 + lane]);
            }
        }
    } else if (cnt > 64) {
        // rare fallback: two-pass serial
        float m = -1e30f;
        for (int t = beg + lane; t < end; t += 64) {
            int e = g_csr[t];
            float qv = GATHER ? 0.5f * (g_q[g1[e]] + g_q[g2[e]]) : g_qe[e];
            float l = qv + g_p0[it][see[2 * (size_t)e]] + g_p1[it][see[2 * (size_t)e + 1]];
            l = l > 0.f ? l : 0.2f * l;
            m = fmaxf(m, l);
        }
        WREDMAX(m);
        float den = 0.f;
        for (int t = beg + lane; t < end; t += 64) {
            int e = g_csr[t];
            float qv = GATHER ? 0.5f * (g_q[g1[e]] + g_q[g2[e]]) : g_qe[e];
            float l = qv + g_p0[it][see[2 * (size_t)e]] + g_p1[it][see[2 * (size_t)e + 1]];
            l = l > 0.f ? l : 0.2f * l;
            den += __expf(l - m);
        }
        WREDUCE(den);
        float rden = 1.f / den;
        for (int t = beg; t < end; t++) {
            int e = g_csr[t];
            float qv = GATHER ? 0.5f * (g_q[g1[e]] + g_q[g2[e]]) : g_qe[e];
            float l = qv + g_p0[it][see[2 * (size_t)e]] + g_p1[it][see[2 * (size_t)e + 1]];
            l = l > 0.f ? l : 0.2f * l;
            float w = __expf(l - m) * rden;
            if (GATHER) {
                float wh = 0.5f * w;
                size_t b1 = (size_t)g1[e] * 64 + lane, b2 = (size_t)g2[e] * 64 + lane;
                if (NCM == 3) {
                    acc[0] += wh * (bfs(g_tfp[b1]) + bfs(g_tfp[b2]));
                    acc[1] += wh * (bfs(g_tfp[PSZ + b1]) + bfs(g_tfp[PSZ + b2]));
                    acc[2] += wh * (bfs(g_tfp[3 * PSZ + b1]) + bfs(g_tfp[3 * PSZ + b2]));
                } else {
                    acc[0] += wh * (bfs(g_tfp[b1]) + bfs(g_tfp[b2]));
                    acc[1] += wh * (bfs(g_tfp[3 * PSZ + b1]) + bfs(g_tfp[3 * PSZ + b2]));
                }
            } else {
                acc[0] += w * bfs(g_msg0h[(size_t)e * 64 + lane]);
            }
        }
    }
#pragma unroll
    for (int c = 0; c < NCM; c++)
        g_msumh[(size_t)seg * 192 + lane + 64 * c] = f2bf(acc[c]);
}

// ----- segment GEMM (64-row x 64-col tiles, K=D): plane cslot = mask*elu(msumh @ W + b) -----
template <int NC>
__global__ __launch_bounds__(256) void k_gemm2(const float* __restrict__ W,
                                               const float* __restrict__ bias) {
    constexpr int D = 64 * NC;
    __shared__ float As[32][68];   // [k][row]
    __shared__ float Bs[32][68];   // [k][col]
    int tid = threadIdx.x;
    int rb0 = blockIdx.x * 64;
    int cslot = blockIdx.y;
    int cb0 = cslot * 64;
    int ty = tid >> 4, tx = tid & 15;   // rows ty*4..+4, cols tx*4..+4
    float acc[4][4];
#pragma unroll
    for (int r = 0; r < 4; r++)
#pragma unroll
        for (int j = 0; j < 4; j++) acc[r][j] = 0.f;

    int arow = tid & 63, aoct = tid >> 6;      // A: row, 8-k octet
    int bk = tid >> 3, bc8 = (tid & 7) * 8;    // B: k, 8-col group
    for (int kk = 0; kk < D; kk += 32) {
        // stage A (transposed): As[k][row] from bf16 msumh
        {
            uint4 u = make_uint4(0, 0, 0, 0);
            if (rb0 + arow < NSEG)
                u = *(const uint4*)&g_msumh[(size_t)(rb0 + arow) * 192 + kk + aoct * 8];
            int kb = aoct * 8;
            As[kb + 0][arow] = bfs((ushort)(u.x & 0xFFFF));
            As[kb + 1][arow] = bfs((ushort)(u.x >> 16));
            As[kb + 2][arow] = bfs((ushort)(u.y & 0xFFFF));
            As[kb + 3][arow] = bfs((ushort)(u.y >> 16));
            As[kb + 4][arow] = bfs((ushort)(u.z & 0xFFFF));
            As[kb + 5][arow] = bfs((ushort)(u.z >> 16));
            As[kb + 6][arow] = bfs((ushort)(u.w & 0xFFFF));
            As[kb + 7][arow] = bfs((ushort)(u.w >> 16));
        }
        // stage B: Bs[k][col] from f32 W
        {
            f4 b0 = *(const f4*)&W[(size_t)(kk + bk) * D + cb0 + bc8];
            f4 b1 = *(const f4*)&W[(size_t)(kk + bk) * D + cb0 + bc8 + 4];
            *(f4*)&Bs[bk][bc8] = b0;
            *(f4*)&Bs[bk][bc8 + 4] = b1;
        }
        __syncthreads();
#pragma unroll
        for (int k = 0; k < 32; k++) {
            f4 a = *(const f4*)&As[k][ty * 4];
            f4 b = *(const f4*)&Bs[k][tx * 4];
            acc[0][0] += a.x * b.x; acc[0][1] += a.x * b.y; acc[0][2] += a.x * b.z; acc[0][3] += a.x * b.w;
            acc[1][0] += a.y * b.x; acc[1][1] += a.y * b.y; acc[1][2] += a.y * b.z; acc[1][3] += a.y * b.w;
            acc[2][0] += a.z * b.x; acc[2][1] += a.z * b.y; acc[2][2] += a.z * b.z; acc[2][3] += a.z * b.w;
            acc[3][0] += a.w * b.x; acc[3][1] += a.w * b.y; acc[3][2] += a.w * b.z; acc[3][3] += a.w * b.w;
        }
        __syncthreads();
    }
#pragma unroll
    for (int r = 0; r < 4; r++) {
        int row = rb0 + ty * 4 + r;
        if (row >= NSEG) continue;
        bool nonempty = g_rowptr[row + 1] > g_rowptr[row];
        ushort4 pk;
        ushort* p = (ushort*)&pk;
#pragma unroll
        for (int j = 0; j < 4; j++) {
            float v = acc[r][j] + bias[cb0 + tx * 4 + j];
            if (!nonempty) v = 0.f;
            v = v > 0.f ? v : (__expf(v) - 1.f);
            p[j] = f2bf(v);
        }
        *(ushort4*)&g_tfp[(size_t)cslot * PSZ + (size_t)row * 64 + tx * 4] = pk;
    }
}

// ---------------- final: per-molecule gather-sum (bf16 planes in, f32 out) ----------------
__global__ void k_final(const int* __restrict__ lscope, float* __restrict__ out) {
    __shared__ int idx[32];
    __shared__ float sm[4][256];
    int m = blockIdx.x, tid = threadIdx.x, w = tid >> 6, lane = tid & 63;
    if (tid < 32) idx[tid] = lscope[m * 32 + tid];
    __syncthreads();
    float a0 = 0.f, a1 = 0.f, a2 = 0.f, a3 = 0.f;
#pragma unroll
    for (int j = w * 8; j < w * 8 + 8; j++) {
        size_t base = (size_t)idx[j] * 64 + lane;
        a0 += bfs(g_tfp[base]);
        a1 += bfs(g_tfp[PSZ + base]);
        a2 += bfs(g_tfp[2 * PSZ + base]);
        a3 += bfs(g_tfp[3 * PSZ + base]);
    }
    sm[w][lane] = a0; sm[w][64 + lane] = a1; sm[w][128 + lane] = a2; sm[w][192 + lane] = a3;
    __syncthreads();
    out[(size_t)m * 256 + tid] = sm[0][tid] + sm[1][tid] + sm[2][tid] + sm[3][tid];
}

extern "C" void kernel_launch(void* const* d_in, const int* in_sizes, int n_in,
                              void* d_out, int out_size, void* d_ws, size_t ws_size,
                              hipStream_t stream) {
    const float* node_feats = (const float*)d_in[0];
    const float* fdg        = (const float*)d_in[1];
    const float* rij        = (const float*)d_in[2];
    const int*   see        = (const int*)d_in[3];
    const int*   b_scope    = (const int*)d_in[4];
    const int*   scope_up   = (const int*)d_in[5];
    const int*   scope_lig  = (const int*)d_in[6];
    const int*   l_scope    = (const int*)d_in[7];
    const float* W_emb      = (const float*)d_in[8];
    const float* b_emb      = (const float*)d_in[9];
    const float* W_dist     = (const float*)d_in[10];
    const float* b_dist     = (const float*)d_in[11];
    const float* fc_W[3]   = {(const float*)d_in[12], (const float*)d_in[15], (const float*)d_in[18]};
    const float* fc_b[3]   = {(const float*)d_in[13], (const float*)d_in[16], (const float*)d_in[19]};
    const float* attn_a[3] = {(const float*)d_in[14], (const float*)d_in[17], (const float*)d_in[20]};

    k_init<<<129, 256, 0, stream>>>();
    k_emb<<<8193, 256, 0, stream>>>(node_feats, W_emb, b_emb,
                                    attn_a[0], attn_a[1], attn_a[2]);
    k_prep_all<<<3, 256, 0, stream>>>(fc_W[0], fc_W[1], fc_W[2],
                                      attn_a[0], attn_a[1], attn_a[2],
                                      fc_b[0], fc_b[1], fc_b[2]);
    k_prep2<<<1, 64, 0, stream>>>(W_dist, b_dist);
    k_msg0<<<NE / 64, 256, 0, stream>>>(fdg, rij, W_dist, b_dist);
    k_hist<<<NE / 256, 256, 0, stream>>>(b_scope);
    k_scan1<<<129, 256, 0, stream>>>();
    k_scan2<<<1, 256, 0, stream>>>(129);
    k_scan3<<<129, 256, 0, stream>>>();
    k_scatter<<<NE / 256, 256, 0, stream>>>(b_scope);

    // iter 0 (message width 64)
    k_attend2<1, false><<<8193, 256, 0, stream>>>(nullptr, nullptr, see, 0);
    k_gemm2<1><<<dim3(513, 1), 256, 0, stream>>>(fc_W[0], fc_b[0]);
    k_nodedot<<<8193, 256, 0, stream>>>(1);
    // iter 1 (message width 128)
    k_attend2<2, true><<<8193, 256, 0, stream>>>(scope_lig, scope_up, see, 1);
    k_gemm2<2><<<dim3(513, 2), 256, 0, stream>>>(fc_W[1], fc_b[1]);
    k_nodedot<<<8193, 256, 0, stream>>>(2);
    // iter 2 (message width 192)
    k_attend2<3, true><<<8193, 256, 0, stream>>>(scope_lig, scope_up, see, 2);
    k_gemm2<3><<<dim3(513, 3), 256, 0, stream>>>(fc_W[2], fc_b[2]);

    k_final<<<2048, 256, 0, stream>>>(l_scope, (float*)d_out);
}

// Round 8
// 322.134 us; speedup vs baseline: 1.1551x; 1.0554x over previous
//
#include <hip/hip_runtime.h>
#include <cstdint>
#include <cstddef>

#define NSEG 32769      // N_NODES + 1 (row 0 is the zero row)
#define NNODES 32768
#define NE 262144
#define PSZ ((size_t)NSEG * 64)   // one tf plane

using f4 = float4;

// ---------------- static device scratch ----------------
// tf planes: g_tfp[plane*PSZ + row*64 + lane], bf16.
// planes 0..2 = GEMM output cols (c*64+lane); plane 3 = h_orig (written once).
__device__ ushort g_tfp[4 * PSZ];
__device__ ushort g_msg0h[(size_t)NE * 64];       // bf16 row-major
__device__ ushort g_msumh[(size_t)NSEG * 192];    // bf16 row-major (K width 192)
__device__ float  g_qe[NE];
__device__ float  g_q[NSEG];
__device__ float  g_p0[3][NSEG];
__device__ float  g_p1[3][NSEG];
__device__ float  g_w2[3][256];                   // w2 = W @ a2 in [0,d); c = a2.b at [255]
__device__ float  g_wq10[10];                     // W_dist @ w2_0
__device__ float  g_cq;                           // b_dist.w2_0 + c0
__device__ int    g_counts[NSEG];
__device__ int    g_excl[NSEG];
__device__ int    g_bsum[1024];
__device__ int    g_rowptr[NSEG + 1];
__device__ int    g_cur[NSEG];
__device__ int    g_csr[NE];

#define WREDUCE(x) { x += __shfl_xor(x, 32); x += __shfl_xor(x, 16); \
                     x += __shfl_xor(x, 8);  x += __shfl_xor(x, 4);  \
                     x += __shfl_xor(x, 2);  x += __shfl_xor(x, 1); }
#define WREDMAX(x) { x = fmaxf(x, __shfl_xor(x, 32)); x = fmaxf(x, __shfl_xor(x, 16)); \
                     x = fmaxf(x, __shfl_xor(x, 8));  x = fmaxf(x, __shfl_xor(x, 4));  \
                     x = fmaxf(x, __shfl_xor(x, 2));  x = fmaxf(x, __shfl_xor(x, 1)); }

__device__ __forceinline__ ushort f2bf(float x) {
    uint u = __float_as_uint(x);
    u += 0x7FFF + ((u >> 16) & 1);
    return (ushort)(u >> 16);
}
__device__ __forceinline__ float bfs(ushort u) { return __uint_as_float(((uint)u) << 16); }

// ---------------- init: zero counts/cur ----------------
__global__ void k_init() {
    int i = blockIdx.x * 256 + threadIdx.x;
    if (i < NSEG) { g_counts[i] = 0; g_cur[i] = 0; }
}

// -------- h_orig (bf16, plane 3) = node_feats @ W_emb + b_emb ; fused p0/p1 --------
__global__ void k_emb(const float* __restrict__ node_feats,
                      const float* __restrict__ W, const float* __restrict__ b,
                      const float* __restrict__ a0, const float* __restrict__ a1,
                      const float* __restrict__ a2) {
    __shared__ float Ws[9 * 64];
    __shared__ float fs[4][9];
    int tid = threadIdx.x;
    for (int i = tid; i < 576; i += 256) Ws[i] = W[i];
    int r0 = blockIdx.x * 4;
    if (tid < 36) {
        int r = r0 + tid / 9, k = tid % 9;
        float v = 0.f;
        if (r >= 1 && r <= NNODES) v = node_feats[(size_t)(r - 1) * 9 + k];
        fs[tid / 9][k] = v;
    }
    __syncthreads();
    int r = tid >> 6, j = tid & 63;
    int row = r0 + r;
    if (row >= NSEG) return;
    float acc = b[j];
#pragma unroll
    for (int k = 0; k < 9; k++) acc += fs[r][k] * Ws[k * 64 + j];
    float v = (row == 0) ? 0.f : acc;
    g_tfp[3 * PSZ + (size_t)row * 64 + j] = f2bf(v);
    const float* A[3] = {a0, a1, a2};
#pragma unroll
    for (int i = 0; i < 3; i++) {
        float d0 = v * A[i][j];
        WREDUCE(d0);
        if (j == 0) g_p0[i][row] = d0;
        float d1 = v * A[i][64 + j];
        WREDUCE(d1);
        if (j == 0) g_p1[i][row] = d1;
    }
}

// ---------------- per-iter prep: w2 = W @ a2 ; c = a2.b (one block per iter) ----------------
__global__ void k_prep_all(const float* __restrict__ W0, const float* __restrict__ W1,
                           const float* __restrict__ W2, const float* __restrict__ a0,
                           const float* __restrict__ a1, const float* __restrict__ a2,
                           const float* __restrict__ b0, const float* __restrict__ b1,
                           const float* __restrict__ b2) {
    int it = blockIdx.x;
    const float* W = it == 0 ? W0 : (it == 1 ? W1 : W2);
    const float* a = it == 0 ? a0 : (it == 1 ? a1 : a2);
    const float* bias = it == 0 ? b0 : (it == 1 ? b1 : b2);
    int d = 64 * (it + 1);
    int k = threadIdx.x;
    if (k < d) {
        float s = 0.f;
        for (int j = 0; j < d; j++) s += W[(size_t)k * d + j] * a[128 + j];
        g_w2[it][k] = s;
    } else if (k == 255) {
        float c = 0.f;
        for (int j = 0; j < d; j++) c += a[128 + j] * bias[j];
        g_w2[it][255] = c;
    }
}

// ---------------- prep2: wq10 = W_dist @ w2_0 ; cq = b_dist.w2_0 + c0 ----------------
__global__ void k_prep2(const float* __restrict__ Wd, const float* __restrict__ bd) {
    int k = threadIdx.x;
    if (k < 10) {
        float s = 0.f;
        for (int j = 0; j < 64; j++) s += Wd[(size_t)k * 64 + j] * g_w2[0][j];
        g_wq10[k] = s;
    } else if (k == 63) {
        float s = 0.f;
        for (int j = 0; j < 64; j++) s += bd[j] * g_w2[0][j];
        g_cq = s + g_w2[0][255];
    }
}

// -------- msg0 (bf16) = [fdg | rij] @ W_dist + b_dist ; qe = x.wq10 + cq --------
__global__ __launch_bounds__(256) void k_msg0(const float* __restrict__ fdg,
                                              const float* __restrict__ rij,
                                              const float* __restrict__ W,
                                              const float* __restrict__ b) {
    __shared__ float Ws[10 * 64];
    __shared__ float bs[64];
    __shared__ float fs[64][10];
    int tid = threadIdx.x;
    for (int i = tid; i < 640; i += 256) Ws[i] = W[i];
    if (tid < 64) bs[tid] = b[tid];
    int e0 = blockIdx.x * 64;
    for (int i = tid; i < 576; i += 256) fs[i / 9][i % 9] = fdg[(size_t)e0 * 9 + i];
    if (tid < 64) fs[tid][9] = rij[e0 + tid];
    __syncthreads();
    int j = tid & 63;
#pragma unroll 4
    for (int p = 0; p < 16; p++) {
        int r = p * 4 + (tid >> 6);
        int e = e0 + r;
        float acc = bs[j];
#pragma unroll
        for (int k = 0; k < 10; k++) acc += fs[r][k] * Ws[k * 64 + j];
        g_msg0h[(size_t)e * 64 + j] = f2bf(acc);
        if (j == 0) {
            float q = g_cq;
#pragma unroll
            for (int k = 0; k < 10; k++) q += fs[r][k] * g_wq10[k];
            g_qe[e] = q;
        }
    }
}

// ---------------- CSR build over b_scope ----------------
__global__ void k_hist(const int* __restrict__ bs) {
    int e = blockIdx.x * 256 + threadIdx.x;
    if (e < NE) atomicAdd(&g_counts[bs[e]], 1);
}

__global__ void k_scan1() {
    __shared__ int s[256];
    int t = threadIdx.x, i = blockIdx.x * 256 + t;
    int v = (i < NSEG) ? g_counts[i] : 0;
    s[t] = v; __syncthreads();
    for (int off = 1; off < 256; off <<= 1) {
        int tmp = (t >= off) ? s[t - off] : 0;
        __syncthreads();
        s[t] += tmp;
        __syncthreads();
    }
    if (i < NSEG) g_excl[i] = s[t] - v;
    if (t == 255) g_bsum[blockIdx.x] = s[255];
}

__global__ void k_scan2(int nb) {
    __shared__ int s[256];
    int t = threadIdx.x;
    int v = (t < nb) ? g_bsum[t] : 0;
    s[t] = v; __syncthreads();
    for (int off = 1; off < 256; off <<= 1) {
        int tmp = (t >= off) ? s[t - off] : 0;
        __syncthreads();
        s[t] += tmp;
        __syncthreads();
    }
    if (t < nb) g_bsum[t] = s[t] - v;   // exclusive
}

__global__ void k_scan3() {
    int i = blockIdx.x * 256 + threadIdx.x;
    if (i < NSEG) g_rowptr[i] = g_excl[i] + g_bsum[i >> 8];
    if (i == NSEG) g_rowptr[NSEG] = NE;
}

__global__ void k_scatter(const int* __restrict__ bs) {
    int e = blockIdx.x * 256 + threadIdx.x;
    if (e < NE) {
        int seg = bs[e];
        int pos = g_rowptr[seg] + atomicAdd(&g_cur[seg], 1);
        g_csr[pos] = e;
    }
}

// ---------------- per-node q = tf . w2 + c  (after iter 1 and 2 GEMMs) ----------------
__global__ void k_nodedot(int it) {
    int tid = threadIdx.x;
    int n = blockIdx.x * 4 + (tid >> 6), lane = tid & 63;
    if (n >= NSEG) return;
    size_t base = (size_t)n * 64 + lane;
    float s;
    if (it == 1)
        s = bfs(g_tfp[base]) * g_w2[1][lane] +
            bfs(g_tfp[3 * PSZ + base]) * g_w2[1][64 + lane];
    else
        s = bfs(g_tfp[base]) * g_w2[2][lane] +
            bfs(g_tfp[PSZ + base]) * g_w2[2][64 + lane] +
            bfs(g_tfp[3 * PSZ + base]) * g_w2[2][128 + lane];
    WREDUCE(s);
    if (lane == 0) g_q[n] = s + g_w2[it][255];
}

// -------- segment softmax (logits fused) + alpha-weighted message sum --------
// message component c -> tf plane (c == NCM-1 ? 3 : c)
template <int NCM, bool GATHER>
__global__ __launch_bounds__(256) void k_attend2(const int* __restrict__ g1,
                                                 const int* __restrict__ g2,
                                                 const int* __restrict__ see, int it) {
    int lane = threadIdx.x & 63;
    int seg = blockIdx.x * 4 + (threadIdx.x >> 6);
    if (seg >= NSEG) return;
    int beg = g_rowptr[seg], end = g_rowptr[seg + 1];
    int cnt = end - beg;
    float acc[NCM];
#pragma unroll
    for (int c = 0; c < NCM; c++) acc[c] = 0.f;

    if (cnt > 0 && cnt <= 64) {
        float l = -1e30f;
        int i1 = 0, i2 = 0;
        if (lane < cnt) {
            int e = g_csr[beg + lane];
            float qv;
            if (GATHER) {
                i1 = g1[e]; i2 = g2[e];
                qv = 0.5f * (g_q[i1] + g_q[i2]);
            } else {
                i1 = e;
                qv = g_qe[e];
            }
            l = qv + g_p0[it][see[2 * (size_t)e]] + g_p1[it][see[2 * (size_t)e + 1]];
            l = l > 0.f ? l : 0.2f * l;
        }
        float m = l;
        WREDMAX(m);
        float ex = (lane < cnt) ? __expf(l - m) : 0.f;
        float den = ex;
        WREDUCE(den);
        float w = ex / den;    // exactly 0 for lanes >= cnt

        // 4-way unrolled, two-phase (issue 24 loads, then FMA). Clamped slots have w==0.
        for (int t0 = 0; t0 < cnt; t0 += 4) {
            float wt4[4];
            int a14[4], a24[4];
#pragma unroll
            for (int u = 0; u < 4; u++) {
                int su = t0 + u; su = su > 63 ? 63 : su;
                wt4[u] = __shfl(w, su);
                if (GATHER) { a14[u] = __shfl(i1, su); a24[u] = __shfl(i2, su); }
                else        { a14[u] = __shfl(i1, su); }
            }
            if (GATHER) {
                ushort va[4][NCM], vb[4][NCM];
#pragma unroll
                for (int u = 0; u < 4; u++) {
                    size_t b1 = (size_t)a14[u] * 64 + lane, b2 = (size_t)a24[u] * 64 + lane;
#pragma unroll
                    for (int c = 0; c < NCM; c++) {
                        size_t po = (size_t)(c == NCM - 1 ? 3 : c) * PSZ;
                        va[u][c] = g_tfp[po + b1];
                        vb[u][c] = g_tfp[po + b2];
                    }
                }
#pragma unroll
                for (int u = 0; u < 4; u++) {
                    float wh = 0.5f * wt4[u];
#pragma unroll
                    for (int c = 0; c < NCM; c++)
                        acc[c] += wh * (bfs(va[u][c]) + bfs(vb[u][c]));
                }
            } else {
                ushort vm[4];
#pragma unroll
                for (int u = 0; u < 4; u++)
                    vm[u] = g_msg0h[(size_t)a14[u] * 64 + lane];
#pragma unroll
                for (int u = 0; u < 4; u++)
                    acc[0] += wt4[u] * bfs(vm[u]);
            }
        }
    } else if (cnt > 64) {
        // rare fallback: two-pass serial
        float m = -1e30f;
        for (int t = beg + lane; t < end; t += 64) {
            int e = g_csr[t];
            float qv = GATHER ? 0.5f * (g_q[g1[e]] + g_q[g2[e]]) : g_qe[e];
            float l = qv + g_p0[it][see[2 * (size_t)e]] + g_p1[it][see[2 * (size_t)e + 1]];
            l = l > 0.f ? l : 0.2f * l;
            m = fmaxf(m, l);
        }
        WREDMAX(m);
        float den = 0.f;
        for (int t = beg + lane; t < end; t += 64) {
            int e = g_csr[t];
            float qv = GATHER ? 0.5f * (g_q[g1[e]] + g_q[g2[e]]) : g_qe[e];
            float l = qv + g_p0[it][see[2 * (size_t)e]] + g_p1[it][see[2 * (size_t)e + 1]];
            l = l > 0.f ? l : 0.2f * l;
            den += __expf(l - m);
        }
        WREDUCE(den);
        float rden = 1.f / den;
        for (int t = beg; t < end; t++) {
            int e = g_csr[t];
            float qv = GATHER ? 0.5f * (g_q[g1[e]] + g_q[g2[e]]) : g_qe[e];
            float l = qv + g_p0[it][see[2 * (size_t)e]] + g_p1[it][see[2 * (size_t)e + 1]];
            l = l > 0.f ? l : 0.2f * l;
            float w = __expf(l - m) * rden;
            if (GATHER) {
                float wh = 0.5f * w;
                size_t b1 = (size_t)g1[e] * 64 + lane, b2 = (size_t)g2[e] * 64 + lane;
                if (NCM == 3) {
                    acc[0] += wh * (bfs(g_tfp[b1]) + bfs(g_tfp[b2]));
                    acc[1] += wh * (bfs(g_tfp[PSZ + b1]) + bfs(g_tfp[PSZ + b2]));
                    acc[2] += wh * (bfs(g_tfp[3 * PSZ + b1]) + bfs(g_tfp[3 * PSZ + b2]));
                } else {
                    acc[0] += wh * (bfs(g_tfp[b1]) + bfs(g_tfp[b2]));
                    acc[1] += wh * (bfs(g_tfp[3 * PSZ + b1]) + bfs(g_tfp[3 * PSZ + b2]));
                }
            } else {
                acc[0] += w * bfs(g_msg0h[(size_t)e * 64 + lane]);
            }
        }
    }
#pragma unroll
    for (int c = 0; c < NCM; c++)
        g_msumh[(size_t)seg * 192 + lane + 64 * c] = f2bf(acc[c]);
}

// ----- segment GEMM (64-row x 64-col tiles, K=D): plane cslot = mask*elu(msumh @ W + b) -----
template <int NC>
__global__ __launch_bounds__(256) void k_gemm2(const float* __restrict__ W,
                                               const float* __restrict__ bias) {
    constexpr int D = 64 * NC;
    __shared__ float As[32][68];   // [k][row]
    __shared__ float Bs[32][68];   // [k][col]
    int tid = threadIdx.x;
    int rb0 = blockIdx.x * 64;
    int cslot = blockIdx.y;
    int cb0 = cslot * 64;
    int ty = tid >> 4, tx = tid & 15;   // rows ty*4..+4, cols tx*4..+4
    float acc[4][4];
#pragma unroll
    for (int r = 0; r < 4; r++)
#pragma unroll
        for (int j = 0; j < 4; j++) acc[r][j] = 0.f;

    int arow = tid & 63, aoct = tid >> 6;      // A: row, 8-k octet
    int bk = tid >> 3, bc8 = (tid & 7) * 8;    // B: k, 8-col group
    for (int kk = 0; kk < D; kk += 32) {
        // stage A (transposed): As[k][row] from bf16 msumh
        {
            uint4 u = make_uint4(0, 0, 0, 0);
            if (rb0 + arow < NSEG)
                u = *(const uint4*)&g_msumh[(size_t)(rb0 + arow) * 192 + kk + aoct * 8];
            int kb = aoct * 8;
            As[kb + 0][arow] = bfs((ushort)(u.x & 0xFFFF));
            As[kb + 1][arow] = bfs((ushort)(u.x >> 16));
            As[kb + 2][arow] = bfs((ushort)(u.y & 0xFFFF));
            As[kb + 3][arow] = bfs((ushort)(u.y >> 16));
            As[kb + 4][arow] = bfs((ushort)(u.z & 0xFFFF));
            As[kb + 5][arow] = bfs((ushort)(u.z >> 16));
            As[kb + 6][arow] = bfs((ushort)(u.w & 0xFFFF));
            As[kb + 7][arow] = bfs((ushort)(u.w >> 16));
        }
        // stage B: Bs[k][col] from f32 W
        {
            f4 b0 = *(const f4*)&W[(size_t)(kk + bk) * D + cb0 + bc8];
            f4 b1 = *(const f4*)&W[(size_t)(kk + bk) * D + cb0 + bc8 + 4];
            *(f4*)&Bs[bk][bc8] = b0;
            *(f4*)&Bs[bk][bc8 + 4] = b1;
        }
        __syncthreads();
#pragma unroll
        for (int k = 0; k < 32; k++) {
            f4 a = *(const f4*)&As[k][ty * 4];
            f4 b = *(const f4*)&Bs[k][tx * 4];
            acc[0][0] += a.x * b.x; acc[0][1] += a.x * b.y; acc[0][2] += a.x * b.z; acc[0][3] += a.x * b.w;
            acc[1][0] += a.y * b.x; acc[1][1] += a.y * b.y; acc[1][2] += a.y * b.z; acc[1][3] += a.y * b.w;
            acc[2][0] += a.z * b.x; acc[2][1] += a.z * b.y; acc[2][2] += a.z * b.z; acc[2][3] += a.z * b.w;
            acc[3][0] += a.w * b.x; acc[3][1] += a.w * b.y; acc[3][2] += a.w * b.z; acc[3][3] += a.w * b.w;
        }
        __syncthreads();
    }
#pragma unroll
    for (int r = 0; r < 4; r++) {
        int row = rb0 + ty * 4 + r;
        if (row >= NSEG) continue;
        bool nonempty = g_rowptr[row + 1] > g_rowptr[row];
        ushort4 pk;
        ushort* p = (ushort*)&pk;
#pragma unroll
        for (int j = 0; j < 4; j++) {
            float v = acc[r][j] + bias[cb0 + tx * 4 + j];
            if (!nonempty) v = 0.f;
            v = v > 0.f ? v : (__expf(v) - 1.f);
            p[j] = f2bf(v);
        }
        *(ushort4*)&g_tfp[(size_t)cslot * PSZ + (size_t)row * 64 + tx * 4] = pk;
    }
}

// ---------------- final: per-molecule gather-sum (bf16 planes in, f32 out) ----------------
__global__ void k_final(const int* __restrict__ lscope, float* __restrict__ out) {
    __shared__ int idx[32];
    __shared__ float sm[4][256];
    int m = blockIdx.x, tid = threadIdx.x, w = tid >> 6, lane = tid & 63;
    if (tid < 32) idx[tid] = lscope[m * 32 + tid];
    __syncthreads();
    float a0 = 0.f, a1 = 0.f, a2 = 0.f, a3 = 0.f;
#pragma unroll
    for (int j = w * 8; j < w * 8 + 8; j++) {
        size_t base = (size_t)idx[j] * 64 + lane;
        a0 += bfs(g_tfp[base]);
        a1 += bfs(g_tfp[PSZ + base]);
        a2 += bfs(g_tfp[2 * PSZ + base]);
        a3 += bfs(g_tfp[3 * PSZ + base]);
    }
    sm[w][lane] = a0; sm[w][64 + lane] = a1; sm[w][128 + lane] = a2; sm[w][192 + lane] = a3;
    __syncthreads();
    out[(size_t)m * 256 + tid] = sm[0][tid] + sm[1][tid] + sm[2][tid] + sm[3][tid];
}

extern "C" void kernel_launch(void* const* d_in, const int* in_sizes, int n_in,
                              void* d_out, int out_size, void* d_ws, size_t ws_size,
                              hipStream_t stream) {
    const float* node_feats = (const float*)d_in[0];
    const float* fdg        = (const float*)d_in[1];
    const float* rij        = (const float*)d_in[2];
    const int*   see        = (const int*)d_in[3];
    const int*   b_scope    = (const int*)d_in[4];
    const int*   scope_up   = (const int*)d_in[5];
    const int*   scope_lig  = (const int*)d_in[6];
    const int*   l_scope    = (const int*)d_in[7];
    const float* W_emb      = (const float*)d_in[8];
    const float* b_emb      = (const float*)d_in[9];
    const float* W_dist     = (const float*)d_in[10];
    const float* b_dist     = (const float*)d_in[11];
    const float* fc_W[3]   = {(const float*)d_in[12], (const float*)d_in[15], (const float*)d_in[18]};
    const float* fc_b[3]   = {(const float*)d_in[13], (const float*)d_in[16], (const float*)d_in[19]};
    const float* attn_a[3] = {(const float*)d_in[14], (const float*)d_in[17], (const float*)d_in[20]};

    k_init<<<129, 256, 0, stream>>>();
    k_emb<<<8193, 256, 0, stream>>>(node_feats, W_emb, b_emb,
                                    attn_a[0], attn_a[1], attn_a[2]);
    k_prep_all<<<3, 256, 0, stream>>>(fc_W[0], fc_W[1], fc_W[2],
                                      attn_a[0], attn_a[1], attn_a[2],
                                      fc_b[0], fc_b[1], fc_b[2]);
    k_prep2<<<1, 64, 0, stream>>>(W_dist, b_dist);
    k_msg0<<<NE / 64, 256, 0, stream>>>(fdg, rij, W_dist, b_dist);
    k_hist<<<NE / 256, 256, 0, stream>>>(b_scope);
    k_scan1<<<129, 256, 0, stream>>>();
    k_scan2<<<1, 256, 0, stream>>>(129);
    k_scan3<<<129, 256, 0, stream>>>();
    k_scatter<<<NE / 256, 256, 0, stream>>>(b_scope);

    // iter 0 (message width 64)
    k_attend2<1, false><<<8193, 256, 0, stream>>>(nullptr, nullptr, see, 0);
    k_gemm2<1><<<dim3(513, 1), 256, 0, stream>>>(fc_W[0], fc_b[0]);
    k_nodedot<<<8193, 256, 0, stream>>>(1);
    // iter 1 (message width 128)
    k_attend2<2, true><<<8193, 256, 0, stream>>>(scope_lig, scope_up, see, 1);
    k_gemm2<2><<<dim3(513, 2), 256, 0, stream>>>(fc_W[1], fc_b[1]);
    k_nodedot<<<8193, 256, 0, stream>>>(2);
    // iter 2 (message width 192)
    k_attend2<3, true><<<8193, 256, 0, stream>>>(scope_lig, scope_up, see, 2);
    k_gemm2<3><<<dim3(513, 3), 256, 0, stream>>>(fc_W[2], fc_b[2]);

    k_final<<<2048, 256, 0, stream>>>(l_scope, (float*)d_out);
}